// Round 1
// baseline (231.111 us; speedup 1.0000x reference)
//
#include <hip/hip_runtime.h>

// Swin shifted-window attention block, MI355X (gfx950)
// B=16, H=W=56, C=512, nh=16, hd=32, window 7x7 (N=49), shift 3.
// One wave (64 threads) per (window, head). Lane r (<49) owns output row r.
// K/V rows are wave-uniform -> scalar (SGPR) loads; q row + softmax + PV
// accumulation fully per-lane in registers. No LDS, no barriers.

constexpr int WSZ  = 7;
constexpr int NTOK = 49;
constexpr int NH_  = 16;
constexpr int HD_  = 32;
constexpr int SP   = 56;   // H == W == 56
constexpr int CH   = 512;  // channels

__global__ __launch_bounds__(64)
void swin_block_kernel(const float* __restrict__ qg,
                       const float* __restrict__ kg,
                       const float* __restrict__ vg,
                       const float* __restrict__ bias,
                       float* __restrict__ outg)
{
    const int wh = blockIdx.x;          // window-head id
    const int h  = wh & (NH_ - 1);      // head
    const int w  = wh >> 4;             // global window id
    const int wc = w & 7;               // window col
    const int wr = (w >> 3) & 7;        // window row
    const int b  = w >> 6;              // batch

    const int lane = threadIdx.x;       // 0..63
    const int rr   = lane < NTOK ? lane : NTOK - 1;  // clamp idle lanes
    const int i    = rr / WSZ;
    const int j    = rr - i * WSZ;

    // padded (shifted-image) coords of this token
    const int hp = wr * WSZ + i;
    const int wp = wc * WSZ + j;
    // source (= destination) coords in the unshifted tensor: (pos+3) mod 56
    int sr = hp + 3; if (sr >= SP) sr -= SP;
    int sc = wp + 3; if (sc >= SP) sc -= SP;

    const int rowoff = ((b * SP + sr) * SP + sc) * CH + h * HD_;

    // region id for the shift mask (built on padded coords hp, wp)
    const int reg_r = (hp < 49 ? 0 : (hp < 53 ? 3 : 6))
                    + (wp < 49 ? 0 : (wp < 53 ? 1 : 2));

    constexpr float LOG2E = 1.4426950408889634f;
    const float qscale = 0.17677669529663687f * LOG2E;  // (1/sqrt(32)) * log2(e)

    // load q row, pre-scaled into exp2 domain
    float qr[HD_];
    {
        const float4* qp = reinterpret_cast<const float4*>(qg + rowoff);
#pragma unroll
        for (int t = 0; t < HD_ / 4; ++t) {
            float4 x = qp[t];
            qr[4*t+0] = x.x * qscale;
            qr[4*t+1] = x.y * qscale;
            qr[4*t+2] = x.z * qscale;
            qr[4*t+3] = x.w * qscale;
        }
    }

    // lane-dependent part of the relative-position-bias index, times 16 (+h)
    const int biaslane = (i * 13 + j) * 16 + h;

    float o[HD_];
#pragma unroll
    for (int d = 0; d < HD_; ++d) o[d] = 0.f;
    float denom = 0.f;

    // (b, head)-base for k/v; per-row offsets are wave-uniform -> s_load
    const float* kb = kg + b * SP * SP * CH + h * HD_;
    const float* vb = vg + b * SP * SP * CH + h * HD_;

    for (int ic = 0; ic < WSZ; ++ic) {   // chunk = one source window-row (i_c = ic)
        const int hpc = wr * WSZ + ic;
        int src_r = hpc + 3; if (src_r >= SP) src_r -= SP;
        const int regh_c = (hpc < 49 ? 0 : (hpc < 53 ? 3 : 6));
        const float* krow0 = kb + src_r * SP * CH;
        const float* vrow0 = vb + src_r * SP * CH;

        float e[WSZ];
#pragma unroll
        for (int u = 0; u < WSZ; ++u) {  // j_c = u
            const int wpc = wc * WSZ + u;
            int src_c = wpc + 3; if (src_c >= SP) src_c -= SP;
            const int reg_c = regh_c + (wpc < 49 ? 0 : (wpc < 53 ? 1 : 2));
            const float* krow = krow0 + src_c * CH;   // wave-uniform

            // bias index: ((i-ic+6)*13 + (j-u+6))*16 + h
            const float bv = bias[biaslane + ((6 - ic) * 13 + (6 - u)) * 16];
            // exp2-domain logit; constant -23 shift (softmax shift-invariant);
            // masked: -100*log2e - 23 = -167.2695...
            float s = fmaf(bv, LOG2E, (reg_r != reg_c) ? -167.26950408889634f
                                                       : -23.0f);
#pragma unroll
            for (int d = 0; d < HD_; ++d) s = fmaf(qr[d], krow[d], s);
            e[u] = exp2f(s);
            denom += e[u];
        }
#pragma unroll
        for (int u = 0; u < WSZ; ++u) {
            const int wpc = wc * WSZ + u;
            int src_c = wpc + 3; if (src_c >= SP) src_c -= SP;
            const float* vrow = vrow0 + src_c * CH;   // wave-uniform
            const float ev = e[u];
#pragma unroll
            for (int d = 0; d < HD_; ++d) o[d] = fmaf(ev, vrow[d], o[d]);
        }
    }

    const float inv = 1.0f / denom;

    if (lane < NTOK) {
        float4* op = reinterpret_cast<float4*>(outg + rowoff);
#pragma unroll
        for (int t = 0; t < HD_ / 4; ++t) {
            float4 x;
            x.x = o[4*t+0] * inv;
            x.y = o[4*t+1] * inv;
            x.z = o[4*t+2] * inv;
            x.w = o[4*t+3] * inv;
            op[t] = x;
        }
    }
}

extern "C" void kernel_launch(void* const* d_in, const int* in_sizes, int n_in,
                              void* d_out, int out_size, void* d_ws, size_t ws_size,
                              hipStream_t stream) {
    const float* q    = (const float*)d_in[0];
    const float* k    = (const float*)d_in[1];
    const float* v    = (const float*)d_in[2];
    const float* bias = (const float*)d_in[3];
    float* out        = (float*)d_out;

    const int B   = in_sizes[0] / (SP * SP * CH);
    const int nwh = B * (SP / WSZ) * (SP / WSZ) * NH_;   // B * 64 * 16

    hipLaunchKernelGGL(swin_block_kernel, dim3(nwh), dim3(64), 0, stream,
                       q, k, v, bias, out);
}